// Round 11
// baseline (162.246 us; speedup 1.0000x reference)
//
#include <hip/hip_runtime.h>

#define N_NODES 50000
#define N_EDGES 800000
#define IN_CH 128
#define HID_CH 256
#define OUT_CH 128

constexpr int TOTAL_E = N_EDGES + N_NODES;       // edges + self loops in CSR
constexpr int NBKT = 196;                        // buckets of 256 nodes (dst>>8)
constexpr int NBLK_BIN = 128;                    // binning blocks
constexpr int EPB_BIN = N_EDGES / NBLK_BIN;      // 6250 (exact)
constexpr int CNT2D = NBKT * NBLK_BIN;           // 25088
constexpr int SCHUNK = (CNT2D + 1023) / 1024;    // 25 elems/thread in fused scan
constexpr int COLCAP = 5376;                     // bucket edge cap + 256 selfloops

typedef __attribute__((ext_vector_type(8))) short bf16x8;
typedef __attribute__((ext_vector_type(4))) float f32x4;
typedef __attribute__((ext_vector_type(4))) unsigned int u32x4;

// ---------------- bf16 helpers ----------------

__device__ __forceinline__ unsigned int bf16rn(float x) {
    unsigned int u = __float_as_uint(x);
    return (u + 0x7fffu + ((u >> 16) & 1u)) >> 16;   // round-to-nearest-even
}

__device__ __forceinline__ void split2(float x0, float x1,
                                       unsigned int& h, unsigned int& l) {
    unsigned int h0 = bf16rn(x0), h1 = bf16rn(x1);
    float f0 = __uint_as_float(h0 << 16), f1 = __uint_as_float(h1 << 16);
    unsigned int l0 = bf16rn(x0 - f0), l1 = bf16rn(x1 - f1);
    h = h0 | (h1 << 16);
    l = l0 | (l1 << 16);
}

__device__ __forceinline__ bf16x8 asbf(u32x4 v) {
    return __builtin_bit_cast(bf16x8, v);
}

// ---------------- fp32 -> bf16 row copy ----------------

__global__ void k_tobf(const float* __restrict__ x, unsigned short* __restrict__ xb,
                       int n8) {
    int i = blockIdx.x * blockDim.x + threadIdx.x;
    if (i >= n8) return;
    const float4* p = (const float4*)(x + (size_t)i * 8);
    float4 a = p[0], b = p[1];
    u32x4 w;
    w.x = bf16rn(a.x) | (bf16rn(a.y) << 16);
    w.y = bf16rn(a.z) | (bf16rn(a.w) << 16);
    w.z = bf16rn(b.x) | (bf16rn(b.y) << 16);
    w.w = bf16rn(b.z) | (bf16rn(b.w) << 16);
    *(u32x4*)(xb + (size_t)i * 8) = w;
}

// ------------- CSR build: LDS radix binning (R9-proven) -------------

__global__ __launch_bounds__(256)
void k_count(const int* __restrict__ dst, int* __restrict__ cnt2D) {
    __shared__ int h[NBKT];
    int b = blockIdx.x, t = threadIdx.x;
    if (t < NBKT) h[t] = 0;
    __syncthreads();
    int e0 = b * EPB_BIN;
    for (int i = t; i < EPB_BIN; i += 256)
        atomicAdd(&h[dst[e0 + i] >> 8], 1);
    __syncthreads();
    if (t < NBKT) cnt2D[t * NBLK_BIN + b] = h[t];
}

// fused exclusive scan of cnt2D -> off2D (one block; 25 elems/thread in regs)
__global__ __launch_bounds__(1024)
void k_scanall(const int* __restrict__ cnt, int* __restrict__ offo) {
    __shared__ int s[1024];
    int t = threadIdx.x;
    int i0 = t * SCHUNK;
    int loc[SCHUNK];
    int sum = 0;
    #pragma unroll
    for (int k = 0; k < SCHUNK; ++k) {
        int i = i0 + k;
        int vv = (i < CNT2D) ? cnt[i] : 0;
        loc[k] = sum;              // exclusive prefix within thread
        sum += vv;
    }
    s[t] = sum; __syncthreads();
    for (int o = 1; o < 1024; o <<= 1) {
        int a = (t >= o) ? s[t - o] : 0;
        __syncthreads();
        s[t] += a;
        __syncthreads();
    }
    int base = s[t] - sum;         // exclusive across threads
    #pragma unroll
    for (int k = 0; k < SCHUNK; ++k) {
        int i = i0 + k;
        if (i < CNT2D) offo[i] = base + loc[k];
    }
    if (t == 0) offo[CNT2D] = N_EDGES;
}

__global__ __launch_bounds__(256)
void k_bin(const int* __restrict__ src, const int* __restrict__ dst,
           const int* __restrict__ off2D, int2* __restrict__ binned) {
    __shared__ int cur[NBKT];
    int b = blockIdx.x, t = threadIdx.x;
    if (t < NBKT) cur[t] = off2D[t * NBLK_BIN + b];
    __syncthreads();
    int e0 = b * EPB_BIN;
    for (int i = t; i < EPB_BIN; i += 256) {
        int d = dst[e0 + i];
        int pos = atomicAdd(&cur[d >> 8], 1);
        int2 p; p.x = src[e0 + i]; p.y = d;
        binned[pos] = p;
    }
}

__global__ __launch_bounds__(256)
void k_csr(const int2* __restrict__ binned, const int* __restrict__ off2D,
           int* __restrict__ col, int* __restrict__ off, float* __restrict__ dis) {
    __shared__ int cnt[256], sc[256], cur[256];
    __shared__ int colL[COLCAP];
    int kb = blockIdx.x, t = threadIdx.x;
    int base2 = off2D[kb * NBLK_BIN];
    int end2  = off2D[(kb + 1) * NBLK_BIN];   // kb==NBKT-1 hits sentinel
    int nE = end2 - base2;
    int nn = min(256, N_NODES - kb * 256);
    cnt[t] = 0;
    __syncthreads();
    for (int i = t; i < nE; i += 256)
        atomicAdd(&cnt[binned[base2 + i].y & 255], 1);
    __syncthreads();
    sc[t] = cnt[t];
    __syncthreads();
    for (int o = 1; o < 256; o <<= 1) {
        int a = (t >= o) ? sc[t - o] : 0;
        __syncthreads();
        sc[t] += a;
        __syncthreads();
    }
    int excl = sc[t] - cnt[t];
    cur[t] = excl + t;            // +t: one self-loop slot per preceding node
    __syncthreads();
    for (int i = t; i < nE; i += 256) {
        int2 p = binned[base2 + i];
        colL[atomicAdd(&cur[p.y & 255], 1)] = p.x;
    }
    __syncthreads();
    int v = kb * 256 + t;
    if (t < nn) {
        colL[cur[t]] = v;         // self loop at segment end
        off[v] = base2 + kb * 256 + excl + t;
        dis[v] = rsqrtf((float)(cnt[t] + 1));
    }
    if (kb == NBKT - 1 && t == 0) off[N_NODES] = TOTAL_E;
    __syncthreads();
    int tot = nE + nn, gbase = base2 + kb * 256;
    for (int i = t; i < tot; i += 256)
        col[gbase + i] = colL[i];
}

// ---- bf16 aggregation, 4-rows-per-load: out[v] = sum_c dis[c]*dis[v]*featb[c] ----
// One node per wave, 4 waves/block. Lane layout: eg = lane>>4 (edge slot 0..3),
// h = lane&15 (channel octet). Each load: uint4 = 16 B -> 4 rows per wave-load.
// Unroll 4 steps (16 edges) -> 4 loads in flight. Reduce via shfl_xor(16,32).

template<bool BIAS, bool RELU, bool BF16OUT>
__global__ __launch_bounds__(256)
void k_agg4(const unsigned short* __restrict__ featb, const int* __restrict__ col,
            const int* __restrict__ off, const float* __restrict__ dis,
            const float* __restrict__ bias, void* __restrict__ outv) {
    int wid  = threadIdx.x >> 6;
    int lane = threadIdx.x & 63;
    int v = blockIdx.x * 4 + wid;          // grid is exactly N_NODES/4
    int start = off[v];
    int lenv  = off[v + 1] - start;
    float disv = dis[v];
    int eg = lane >> 4;                    // edge slot within step
    int h  = lane & 15;                    // channel octet: ch h*8..h*8+7
    float acc[8] = {0.f, 0.f, 0.f, 0.f, 0.f, 0.f, 0.f, 0.f};
    for (int base = 0; base < lenv; base += 64) {
        int n = min(64, lenv - base);
        int   cv = 0;
        float wv = 0.f;
        if (lane < n) {
            cv = col[start + base + lane];
            wv = dis[cv] * disv;
        }
        auto step = [&](int j) {           // edges j..j+3 (j+eg>=n -> w=0, c=0)
            int   c = __shfl(cv, j + eg);
            float w = __shfl(wv, j + eg);
            uint4 d = *(const uint4*)&featb[(size_t)c * 128 + h * 8];
            acc[0] = fmaf(w, __uint_as_float(d.x << 16),         acc[0]);
            acc[1] = fmaf(w, __uint_as_float(d.x & 0xffff0000u), acc[1]);
            acc[2] = fmaf(w, __uint_as_float(d.y << 16),         acc[2]);
            acc[3] = fmaf(w, __uint_as_float(d.y & 0xffff0000u), acc[3]);
            acc[4] = fmaf(w, __uint_as_float(d.z << 16),         acc[4]);
            acc[5] = fmaf(w, __uint_as_float(d.z & 0xffff0000u), acc[5]);
            acc[6] = fmaf(w, __uint_as_float(d.w << 16),         acc[6]);
            acc[7] = fmaf(w, __uint_as_float(d.w & 0xffff0000u), acc[7]);
        };
        int j = 0;
        for (; j + 16 <= n; j += 16) { step(j); step(j + 4); step(j + 8); step(j + 12); }
        for (; j < n; j += 4) step(j);
    }
    #pragma unroll
    for (int k = 0; k < 8; ++k) {
        acc[k] += __shfl_xor(acc[k], 16);
        acc[k] += __shfl_xor(acc[k], 32);
    }
    if (eg == 0) {                         // lanes 0..15 hold channels h*8..h*8+7
        if (BIAS) {
            #pragma unroll
            for (int k = 0; k < 8; ++k) acc[k] += bias[h * 8 + k];
        }
        if (RELU) {
            #pragma unroll
            for (int k = 0; k < 8; ++k) acc[k] = fmaxf(acc[k], 0.f);
        }
        if (BF16OUT) {
            u32x4 p;
            p.x = bf16rn(acc[0]) | (bf16rn(acc[1]) << 16);
            p.y = bf16rn(acc[2]) | (bf16rn(acc[3]) << 16);
            p.z = bf16rn(acc[4]) | (bf16rn(acc[5]) << 16);
            p.w = bf16rn(acc[6]) | (bf16rn(acc[7]) << 16);
            *(u32x4*)&((unsigned short*)outv)[(size_t)v * 128 + h * 8] = p;
        } else {
            float* op = (float*)outv + (size_t)v * 128 + h * 8;
            *(float4*)op       = make_float4(acc[0], acc[1], acc[2], acc[3]);
            *(float4*)(op + 4) = make_float4(acc[4], acc[5], acc[6], acc[7]);
        }
    }
}

// ---- W split into MFMA-fragment-ordered bf16 hi/lo (both layers, one launch) ----
// Fragment layout (16x16x32 bf16): B col n = lane&15, k = (lane>>4)*8 + i.

template<int K, int NC>
__device__ __forceinline__ void wsplit_body(const float* __restrict__ W,
                                            u32x4* __restrict__ Wf, int tid) {
    constexpr int NT = NC / 16;
    int lane = tid & 63;
    int ntk  = tid >> 6;
    int kt = ntk / NT, nt = ntk % NT;
    int kb = kt * 32 + (lane >> 4) * 8;
    int n  = nt * 16 + (lane & 15);
    unsigned int hh[4], ll[4];
    #pragma unroll
    for (int j = 0; j < 4; ++j) {
        float x0 = W[(size_t)(kb + 2 * j) * NC + n];
        float x1 = W[(size_t)(kb + 2 * j + 1) * NC + n];
        split2(x0, x1, hh[j], ll[j]);
    }
    Wf[(size_t)(ntk * 2 + 0) * 64 + lane] = (u32x4){hh[0], hh[1], hh[2], hh[3]};
    Wf[(size_t)(ntk * 2 + 1) * 64 + lane] = (u32x4){ll[0], ll[1], ll[2], ll[3]};
}

__global__ void k_wsplit_both(const float* __restrict__ W1, u32x4* __restrict__ Wf1,
                              const float* __restrict__ W2, u32x4* __restrict__ Wf2) {
    int tid = blockIdx.x * blockDim.x + threadIdx.x;
    if (tid < 4096)      wsplit_body<IN_CH,  HID_CH>(W1, Wf1, tid);
    else if (tid < 8192) wsplit_body<HID_CH, OUT_CH>(W2, Wf2, tid - 4096);
}

// ---- Fused GEMM: t2 = relu(Ab@W1+b1) @ W2; Ab bf16 [M,128], t2 bf16 [M,128] ----
// 4 waves/block, 32 rows/block. A single-bf16, W hi/lo (2-pass MFMA).
// h1 tile (32x256) lives only in LDS as single bf16 (XOR-swizzled), 16 KB.

__global__ __launch_bounds__(256)
void k_gemm_fused(const unsigned short* __restrict__ Ab, const u32x4* __restrict__ Wf1,
                  const float* __restrict__ b1, const u32x4* __restrict__ Wf2,
                  unsigned short* __restrict__ outb, int M) {
    __shared__ unsigned short hh[32 * 256];
    int lane = threadIdx.x & 63, wid = threadIdx.x >> 6;
    int lq = lane >> 4, lr = lane & 15, kq = lq * 8;
    int rbase = blockIdx.x * 32;

    // ---- GEMM1: 32x128 @ 128x256; each wave owns 4 of 16 N-tiles ----
    f32x4 acc[2][4];
    #pragma unroll
    for (int s = 0; s < 2; ++s)
        #pragma unroll
        for (int t = 0; t < 4; ++t) acc[s][t] = (f32x4){0.f, 0.f, 0.f, 0.f};

    for (int kt = 0; kt < 4; ++kt) {
        bf16x8 ah[2];
        #pragma unroll
        for (int s = 0; s < 2; ++s) {
            int row = min(rbase + s * 16 + lr, M - 1);
            ah[s] = *(const bf16x8*)&Ab[(size_t)row * IN_CH + kt * 32 + kq];
        }
        #pragma unroll
        for (int t = 0; t < 4; ++t) {
            int nt = wid * 4 + t;
            const u32x4* wp = Wf1 + (size_t)((kt * 16 + nt) * 2) * 64 + lane;
            bf16x8 bh = asbf(wp[0]);
            bf16x8 bl = asbf(wp[64]);
            acc[0][t] = __builtin_amdgcn_mfma_f32_16x16x32_bf16(ah[0], bh, acc[0][t], 0, 0, 0);
            acc[1][t] = __builtin_amdgcn_mfma_f32_16x16x32_bf16(ah[1], bh, acc[1][t], 0, 0, 0);
            acc[0][t] = __builtin_amdgcn_mfma_f32_16x16x32_bf16(ah[0], bl, acc[0][t], 0, 0, 0);
            acc[1][t] = __builtin_amdgcn_mfma_f32_16x16x32_bf16(ah[1], bl, acc[1][t], 0, 0, 0);
        }
    }

    // epilogue1: bias+relu -> single bf16 into LDS (XOR-swizzled rows)
    #pragma unroll
    for (int t = 0; t < 4; ++t) {
        int colg = (wid * 4 + t) * 16 + lr;
        float bv = b1[colg];
        #pragma unroll
        for (int s = 0; s < 2; ++s) {
            #pragma unroll
            for (int j = 0; j < 4; ++j) {
                int row = s * 16 + lq * 4 + j;
                float o = fmaxf(acc[s][t][j] + bv, 0.f);
                int e = (row * 256 + colg) ^ ((row & 7) << 3);
                hh[e] = (unsigned short)bf16rn(o);
            }
        }
    }
    __syncthreads();

    // ---- GEMM2: 32x256 @ 256x128; each wave owns 2 of 8 N-tiles ----
    f32x4 acc2[2][2];
    #pragma unroll
    for (int s = 0; s < 2; ++s)
        #pragma unroll
        for (int t = 0; t < 2; ++t) acc2[s][t] = (f32x4){0.f, 0.f, 0.f, 0.f};

    for (int kt = 0; kt < 8; ++kt) {
        bf16x8 ah[2];
        #pragma unroll
        for (int s = 0; s < 2; ++s) {
            int row = s * 16 + lr;
            int e = (row * 256 + kt * 32 + kq) ^ ((row & 7) << 3);
            ah[s] = *(const bf16x8*)&hh[e];
        }
        #pragma unroll
        for (int t = 0; t < 2; ++t) {
            int nt = wid * 2 + t;
            const u32x4* wp = Wf2 + (size_t)((kt * 8 + nt) * 2) * 64 + lane;
            bf16x8 bh = asbf(wp[0]);
            bf16x8 bl = asbf(wp[64]);
            acc2[0][t] = __builtin_amdgcn_mfma_f32_16x16x32_bf16(ah[0], bh, acc2[0][t], 0, 0, 0);
            acc2[1][t] = __builtin_amdgcn_mfma_f32_16x16x32_bf16(ah[1], bh, acc2[1][t], 0, 0, 0);
            acc2[0][t] = __builtin_amdgcn_mfma_f32_16x16x32_bf16(ah[0], bl, acc2[0][t], 0, 0, 0);
            acc2[1][t] = __builtin_amdgcn_mfma_f32_16x16x32_bf16(ah[1], bl, acc2[1][t], 0, 0, 0);
        }
    }

    // epilogue2: t2 as bf16 (bias/relu applied by agg2)
    #pragma unroll
    for (int t = 0; t < 2; ++t) {
        int colg = (wid * 2 + t) * 16 + lr;
        #pragma unroll
        for (int s = 0; s < 2; ++s) {
            #pragma unroll
            for (int j = 0; j < 4; ++j) {
                int row = rbase + s * 16 + lq * 4 + j;
                if (row < M)
                    outb[(size_t)row * OUT_CH + colg] =
                        (unsigned short)bf16rn(acc2[s][t][j]);
            }
        }
    }
}

// ---------------- launch ----------------

extern "C" void kernel_launch(void* const* d_in, const int* in_sizes, int n_in,
                              void* d_out, int out_size, void* d_ws, size_t ws_size,
                              hipStream_t stream) {
    const float* x   = (const float*)d_in[0];
    const int*   ei  = (const int*)d_in[1];
    const int*   src = ei;
    const int*   dst = ei + N_EDGES;
    const float* W1  = (const float*)d_in[3];
    const float* b1  = (const float*)d_in[4];
    const float* W2  = (const float*)d_in[5];
    const float* b2  = (const float*)d_in[6];
    float* out = (float*)d_out;

    char* ws = (char*)d_ws;
    size_t o = 0;
    auto carve = [&](size_t bytes) {
        void* p = ws + o;
        o += (bytes + 255) & ~(size_t)255;
        return p;
    };
    int*   cnt2D  = (int*)  carve((size_t)CNT2D * 4);
    int*   off2D  = (int*)  carve((size_t)(CNT2D + 1) * 4);
    int*   off    = (int*)  carve((size_t)(N_NODES + 1) * 4);
    float* dis    = (float*)carve(N_NODES * 4);
    int*   col    = (int*)  carve((size_t)TOTAL_E * 4);
    char*  buf1   = (char*) carve((size_t)N_NODES * 128 * 2);  // binned / agg1b
    unsigned short* bfbuf = (unsigned short*)carve((size_t)N_NODES * 128 * 2);
    u32x4* Wf1    = (u32x4*)carve((size_t)4 * 16 * 2 * 64 * 16);
    u32x4* Wf2    = (u32x4*)carve((size_t)8 * 8 * 2 * 64 * 16);
    // Aliases (lifetimes by launch order):
    //   binned aliases buf1 : written by k_bin (6.4 MB), read by k_csr, dead after
    //   agg1b  aliases buf1 : written by agg1 (12.8 MB, after binned dead)
    //   xb  = bfbuf         : written by k_tobf, read by agg1, dead after
    //   t2b = bfbuf         : written by fused gemm (xb dead), read by agg2
    int2*           binned = (int2*)buf1;
    unsigned short* agg1b  = (unsigned short*)buf1;
    unsigned short* xb     = bfbuf;
    unsigned short* t2b    = bfbuf;

    const int B = 256;
    k_tobf    <<<(N_NODES * 128 / 8 + B - 1) / B, B, 0, stream>>>(x, xb, N_NODES * 128 / 8);
    k_count   <<<NBLK_BIN, 256, 0, stream>>>(dst, cnt2D);
    k_scanall <<<1, 1024, 0, stream>>>(cnt2D, off2D);
    k_bin     <<<NBLK_BIN, 256, 0, stream>>>(src, dst, off2D, binned);
    k_csr     <<<NBKT, 256, 0, stream>>>(binned, off2D, col, off, dis);
    k_wsplit_both<<<32, 256, 0, stream>>>(W1, Wf1, W2, Wf2);

    // layer 1 aggregation: agg1b = bf16(A xb)   (overwrites binned, now dead)
    k_agg4<false, false, true><<<N_NODES / 4, 256, 0, stream>>>(
        xb, col, off, dis, nullptr, agg1b);
    // fused GEMMs: t2b = bf16( relu(agg1b@W1+b1) @ W2 )   (overwrites xb, now dead)
    k_gemm_fused<<<(N_NODES + 31) / 32, 256, 0, stream>>>(agg1b, Wf1, b1, Wf2, t2b, N_NODES);
    // layer 2 aggregation: out = relu(A t2b + b2)
    k_agg4<true, true, false><<<N_NODES / 4, 256, 0, stream>>>(
        t2b, col, off, dis, b2, out);
}

// Round 12
// 150.906 us; speedup vs baseline: 1.0751x; 1.0751x over previous
//
#include <hip/hip_runtime.h>

#define N_NODES 50000
#define N_EDGES 800000
#define IN_CH 128
#define HID_CH 256
#define OUT_CH 128

constexpr int TOTAL_E = N_EDGES + N_NODES;       // edges + self loops in CSR
constexpr int NBKT = 196;                        // buckets of 256 nodes (dst>>8)
constexpr int NBLK_BIN = 128;                    // binning blocks
constexpr int EPB_BIN = N_EDGES / NBLK_BIN;      // 6250 (exact)
constexpr int CNT2D = NBKT * NBLK_BIN;           // 25088
constexpr int SCAN_BLK = 1024;
constexpr int NB_SC = (CNT2D + SCAN_BLK - 1) / SCAN_BLK;  // 25
constexpr int COLCAP = 5376;                     // bucket edge cap + 256 selfloops

typedef __attribute__((ext_vector_type(8))) short bf16x8;
typedef __attribute__((ext_vector_type(4))) float f32x4;
typedef __attribute__((ext_vector_type(4))) unsigned int u32x4;

// ---------------- bf16 helpers ----------------

__device__ __forceinline__ unsigned int bf16rn(float x) {
    unsigned int u = __float_as_uint(x);
    return (u + 0x7fffu + ((u >> 16) & 1u)) >> 16;   // round-to-nearest-even
}

__device__ __forceinline__ void split2(float x0, float x1,
                                       unsigned int& h, unsigned int& l) {
    unsigned int h0 = bf16rn(x0), h1 = bf16rn(x1);
    float f0 = __uint_as_float(h0 << 16), f1 = __uint_as_float(h1 << 16);
    unsigned int l0 = bf16rn(x0 - f0), l1 = bf16rn(x1 - f1);
    h = h0 | (h1 << 16);
    l = l0 | (l1 << 16);
}

__device__ __forceinline__ bf16x8 asbf(u32x4 v) {
    return __builtin_bit_cast(bf16x8, v);
}

// ---------------- fp32 -> bf16 row copy ----------------

__global__ void k_tobf(const float* __restrict__ x, unsigned short* __restrict__ xb,
                       int n8) {
    int i = blockIdx.x * blockDim.x + threadIdx.x;
    if (i >= n8) return;
    const float4* p = (const float4*)(x + (size_t)i * 8);
    float4 a = p[0], b = p[1];
    u32x4 w;
    w.x = bf16rn(a.x) | (bf16rn(a.y) << 16);
    w.y = bf16rn(a.z) | (bf16rn(a.w) << 16);
    w.z = bf16rn(b.x) | (bf16rn(b.y) << 16);
    w.w = bf16rn(b.z) | (bf16rn(b.w) << 16);
    *(u32x4*)(xb + (size_t)i * 8) = w;
}

// ------------- CSR build: LDS radix binning (R9-proven) -------------

__global__ __launch_bounds__(256)
void k_count(const int* __restrict__ dst, int* __restrict__ cnt2D) {
    __shared__ int h[NBKT];
    int b = blockIdx.x, t = threadIdx.x;
    if (t < NBKT) h[t] = 0;
    __syncthreads();
    int e0 = b * EPB_BIN;
    for (int i = t; i < EPB_BIN; i += 256)
        atomicAdd(&h[dst[e0 + i] >> 8], 1);
    __syncthreads();
    if (t < NBKT) cnt2D[t * NBLK_BIN + b] = h[t];
}

__global__ void k_scan1(const int* __restrict__ cnt, int* __restrict__ incl,
                        int* __restrict__ part, int n) {
    __shared__ int s[SCAN_BLK];
    int t = threadIdx.x;
    int i = blockIdx.x * SCAN_BLK + t;
    int v = (i < n) ? cnt[i] : 0;
    s[t] = v; __syncthreads();
    for (int o = 1; o < SCAN_BLK; o <<= 1) {
        int a = (t >= o) ? s[t - o] : 0;
        __syncthreads();
        s[t] += a;
        __syncthreads();
    }
    if (i < n) incl[i] = s[t];
    if (t == SCAN_BLK - 1) part[blockIdx.x] = s[t];
}

__global__ void k_scan2(int* __restrict__ part, int n) {
    __shared__ int s[SCAN_BLK];
    int t = threadIdx.x;
    int v = (t < n) ? part[t] : 0;
    s[t] = v; __syncthreads();
    for (int o = 1; o < SCAN_BLK; o <<= 1) {
        int a = (t >= o) ? s[t - o] : 0;
        __syncthreads();
        s[t] += a;
        __syncthreads();
    }
    if (t < n) part[t] = s[t] - v;    // exclusive
}

__global__ void k_off(int* __restrict__ incl, const int* __restrict__ cnt,
                      const int* __restrict__ part, int n, int total) {
    int i = blockIdx.x * blockDim.x + threadIdx.x;
    if (i < n)       incl[i] = part[i >> 10] + incl[i] - cnt[i];
    else if (i == n) incl[i] = total;
}

__global__ __launch_bounds__(256)
void k_bin(const int* __restrict__ src, const int* __restrict__ dst,
           const int* __restrict__ off2D, int2* __restrict__ binned) {
    __shared__ int cur[NBKT];
    int b = blockIdx.x, t = threadIdx.x;
    if (t < NBKT) cur[t] = off2D[t * NBLK_BIN + b];
    __syncthreads();
    int e0 = b * EPB_BIN;
    for (int i = t; i < EPB_BIN; i += 256) {
        int d = dst[e0 + i];
        int pos = atomicAdd(&cur[d >> 8], 1);
        int2 p; p.x = src[e0 + i]; p.y = d;
        binned[pos] = p;
    }
}

__global__ __launch_bounds__(256)
void k_csr(const int2* __restrict__ binned, const int* __restrict__ off2D,
           int* __restrict__ col, int* __restrict__ off, float* __restrict__ dis) {
    __shared__ int cnt[256], sc[256], cur[256];
    __shared__ int colL[COLCAP];
    int kb = blockIdx.x, t = threadIdx.x;
    int base2 = off2D[kb * NBLK_BIN];
    int end2  = off2D[(kb + 1) * NBLK_BIN];   // kb==NBKT-1 hits sentinel
    int nE = end2 - base2;
    int nn = min(256, N_NODES - kb * 256);
    cnt[t] = 0;
    __syncthreads();
    for (int i = t; i < nE; i += 256)
        atomicAdd(&cnt[binned[base2 + i].y & 255], 1);
    __syncthreads();
    sc[t] = cnt[t];
    __syncthreads();
    for (int o = 1; o < 256; o <<= 1) {
        int a = (t >= o) ? sc[t - o] : 0;
        __syncthreads();
        sc[t] += a;
        __syncthreads();
    }
    int excl = sc[t] - cnt[t];
    cur[t] = excl + t;            // +t: one self-loop slot per preceding node
    __syncthreads();
    for (int i = t; i < nE; i += 256) {
        int2 p = binned[base2 + i];
        colL[atomicAdd(&cur[p.y & 255], 1)] = p.x;
    }
    __syncthreads();
    int v = kb * 256 + t;
    if (t < nn) {
        colL[cur[t]] = v;         // self loop at segment end
        off[v] = base2 + kb * 256 + excl + t;
        dis[v] = rsqrtf((float)(cnt[t] + 1));
    }
    if (kb == NBKT - 1 && t == 0) off[N_NODES] = TOTAL_E;
    __syncthreads();
    int tot = nE + nn, gbase = base2 + kb * 256;
    for (int i = t; i < tot; i += 256)
        col[gbase + i] = colL[i];
}

// ---- bf16 aggregation: out[v] = sum_{c} dis[c]*dis[v] * featb[c]  (F = 128) ----
// BF16OUT: write bf16 (feeds the fused GEMM's A directly).

template<bool BIAS, bool RELU, bool BF16OUT>
__global__ __launch_bounds__(256)
void k_agg_bf(const unsigned short* __restrict__ featb, const int* __restrict__ col,
              const int* __restrict__ off, const float* __restrict__ dis,
              const float* __restrict__ bias, void* __restrict__ outv) {
    int wid  = threadIdx.x >> 6;
    int lane = threadIdx.x & 63;
    int v = blockIdx.x * 4 + wid;          // grid is exactly N_NODES/4
    int start = off[v];
    int lenv  = off[v + 1] - start;
    float disv = dis[v];
    int half = lane >> 5;
    int q    = lane & 31;
    float4 acc = make_float4(0.f, 0.f, 0.f, 0.f);
    for (int base = 0; base < lenv; base += 64) {
        int n = min(64, lenv - base);
        int   cv = 0;
        float wv = 0.f;
        if (lane < n) {
            cv = col[start + base + lane];
            wv = dis[cv] * disv;
        }
        auto pair = [&](int j) {
            int   c = __shfl(cv, j + half);   // j+half==n on odd tail -> w=0, c=0
            float w = __shfl(wv, j + half);
            uint2 d = *(const uint2*)&featb[(size_t)c * 128 + q * 4];
            acc.x = fmaf(w, __uint_as_float(d.x << 16),         acc.x);
            acc.y = fmaf(w, __uint_as_float(d.x & 0xffff0000u), acc.y);
            acc.z = fmaf(w, __uint_as_float(d.y << 16),         acc.z);
            acc.w = fmaf(w, __uint_as_float(d.y & 0xffff0000u), acc.w);
        };
        int j = 0;
        for (; j + 8 <= n; j += 8) { pair(j); pair(j + 2); pair(j + 4); pair(j + 6); }
        for (; j < n; j += 2) pair(j);
    }
    acc.x += __shfl_xor(acc.x, 32);
    acc.y += __shfl_xor(acc.y, 32);
    acc.z += __shfl_xor(acc.z, 32);
    acc.w += __shfl_xor(acc.w, 32);
    if (half == 0) {
        float4 o = acc;
        if (BIAS) {
            float4 b = *(const float4*)&bias[q * 4];
            o.x += b.x; o.y += b.y; o.z += b.z; o.w += b.w;
        }
        if (RELU) {
            o.x = fmaxf(o.x, 0.f); o.y = fmaxf(o.y, 0.f);
            o.z = fmaxf(o.z, 0.f); o.w = fmaxf(o.w, 0.f);
        }
        if (BF16OUT) {
            uint2 p;
            p.x = bf16rn(o.x) | (bf16rn(o.y) << 16);
            p.y = bf16rn(o.z) | (bf16rn(o.w) << 16);
            *(uint2*)&((unsigned short*)outv)[(size_t)v * 128 + q * 4] = p;
        } else {
            *(float4*)&((float*)outv)[(size_t)v * 128 + q * 4] = o;
        }
    }
}

// ---- W split into MFMA-fragment-ordered bf16 hi/lo (both layers, one launch) ----
// Fragment layout (16x16x32 bf16): B col n = lane&15, k = (lane>>4)*8 + i.

template<int K, int NC>
__device__ __forceinline__ void wsplit_body(const float* __restrict__ W,
                                            u32x4* __restrict__ Wf, int tid) {
    constexpr int NT = NC / 16;
    int lane = tid & 63;
    int ntk  = tid >> 6;
    int kt = ntk / NT, nt = ntk % NT;
    int kb = kt * 32 + (lane >> 4) * 8;
    int n  = nt * 16 + (lane & 15);
    unsigned int hh[4], ll[4];
    #pragma unroll
    for (int j = 0; j < 4; ++j) {
        float x0 = W[(size_t)(kb + 2 * j) * NC + n];
        float x1 = W[(size_t)(kb + 2 * j + 1) * NC + n];
        split2(x0, x1, hh[j], ll[j]);
    }
    Wf[(size_t)(ntk * 2 + 0) * 64 + lane] = (u32x4){hh[0], hh[1], hh[2], hh[3]};
    Wf[(size_t)(ntk * 2 + 1) * 64 + lane] = (u32x4){ll[0], ll[1], ll[2], ll[3]};
}

__global__ void k_wsplit_both(const float* __restrict__ W1, u32x4* __restrict__ Wf1,
                              const float* __restrict__ W2, u32x4* __restrict__ Wf2) {
    int tid = blockIdx.x * blockDim.x + threadIdx.x;
    if (tid < 4096)      wsplit_body<IN_CH,  HID_CH>(W1, Wf1, tid);
    else if (tid < 8192) wsplit_body<HID_CH, OUT_CH>(W2, Wf2, tid - 4096);
}

// ---- Fused GEMM: t2 = relu(Ab@W1+b1) @ W2; Ab bf16 [M,128], t2 bf16 [M,128] ----
// 4 waves/block, 32 rows/block. A single-bf16, W hi/lo (2-pass MFMA).
// h1 tile (32x256) lives only in LDS as single bf16 (XOR-swizzled), 16 KB.

__global__ __launch_bounds__(256)
void k_gemm_fused(const unsigned short* __restrict__ Ab, const u32x4* __restrict__ Wf1,
                  const float* __restrict__ b1, const u32x4* __restrict__ Wf2,
                  unsigned short* __restrict__ outb, int M) {
    __shared__ unsigned short hh[32 * 256];
    int lane = threadIdx.x & 63, wid = threadIdx.x >> 6;
    int lq = lane >> 4, lr = lane & 15, kq = lq * 8;
    int rbase = blockIdx.x * 32;

    // ---- GEMM1: 32x128 @ 128x256; each wave owns 4 of 16 N-tiles ----
    f32x4 acc[2][4];
    #pragma unroll
    for (int s = 0; s < 2; ++s)
        #pragma unroll
        for (int t = 0; t < 4; ++t) acc[s][t] = (f32x4){0.f, 0.f, 0.f, 0.f};

    for (int kt = 0; kt < 4; ++kt) {
        bf16x8 ah[2];
        #pragma unroll
        for (int s = 0; s < 2; ++s) {
            int row = min(rbase + s * 16 + lr, M - 1);
            ah[s] = *(const bf16x8*)&Ab[(size_t)row * IN_CH + kt * 32 + kq];
        }
        #pragma unroll
        for (int t = 0; t < 4; ++t) {
            int nt = wid * 4 + t;
            const u32x4* wp = Wf1 + (size_t)((kt * 16 + nt) * 2) * 64 + lane;
            bf16x8 bh = asbf(wp[0]);
            bf16x8 bl = asbf(wp[64]);
            acc[0][t] = __builtin_amdgcn_mfma_f32_16x16x32_bf16(ah[0], bh, acc[0][t], 0, 0, 0);
            acc[1][t] = __builtin_amdgcn_mfma_f32_16x16x32_bf16(ah[1], bh, acc[1][t], 0, 0, 0);
            acc[0][t] = __builtin_amdgcn_mfma_f32_16x16x32_bf16(ah[0], bl, acc[0][t], 0, 0, 0);
            acc[1][t] = __builtin_amdgcn_mfma_f32_16x16x32_bf16(ah[1], bl, acc[1][t], 0, 0, 0);
        }
    }

    // epilogue1: bias+relu -> single bf16 into LDS (XOR-swizzled rows)
    #pragma unroll
    for (int t = 0; t < 4; ++t) {
        int colg = (wid * 4 + t) * 16 + lr;
        float bv = b1[colg];
        #pragma unroll
        for (int s = 0; s < 2; ++s) {
            #pragma unroll
            for (int j = 0; j < 4; ++j) {
                int row = s * 16 + lq * 4 + j;
                float o = fmaxf(acc[s][t][j] + bv, 0.f);
                int e = (row * 256 + colg) ^ ((row & 7) << 3);
                hh[e] = (unsigned short)bf16rn(o);
            }
        }
    }
    __syncthreads();

    // ---- GEMM2: 32x256 @ 256x128; each wave owns 2 of 8 N-tiles ----
    f32x4 acc2[2][2];
    #pragma unroll
    for (int s = 0; s < 2; ++s)
        #pragma unroll
        for (int t = 0; t < 2; ++t) acc2[s][t] = (f32x4){0.f, 0.f, 0.f, 0.f};

    for (int kt = 0; kt < 8; ++kt) {
        bf16x8 ah[2];
        #pragma unroll
        for (int s = 0; s < 2; ++s) {
            int row = s * 16 + lr;
            int e = (row * 256 + kt * 32 + kq) ^ ((row & 7) << 3);
            ah[s] = *(const bf16x8*)&hh[e];
        }
        #pragma unroll
        for (int t = 0; t < 2; ++t) {
            int nt = wid * 2 + t;
            const u32x4* wp = Wf2 + (size_t)((kt * 8 + nt) * 2) * 64 + lane;
            bf16x8 bh = asbf(wp[0]);
            bf16x8 bl = asbf(wp[64]);
            acc2[0][t] = __builtin_amdgcn_mfma_f32_16x16x32_bf16(ah[0], bh, acc2[0][t], 0, 0, 0);
            acc2[1][t] = __builtin_amdgcn_mfma_f32_16x16x32_bf16(ah[1], bh, acc2[1][t], 0, 0, 0);
            acc2[0][t] = __builtin_amdgcn_mfma_f32_16x16x32_bf16(ah[0], bl, acc2[0][t], 0, 0, 0);
            acc2[1][t] = __builtin_amdgcn_mfma_f32_16x16x32_bf16(ah[1], bl, acc2[1][t], 0, 0, 0);
        }
    }

    // epilogue2: t2 as bf16 (bias/relu applied by agg2)
    #pragma unroll
    for (int t = 0; t < 2; ++t) {
        int colg = (wid * 2 + t) * 16 + lr;
        #pragma unroll
        for (int s = 0; s < 2; ++s) {
            #pragma unroll
            for (int j = 0; j < 4; ++j) {
                int row = rbase + s * 16 + lq * 4 + j;
                if (row < M)
                    outb[(size_t)row * OUT_CH + colg] =
                        (unsigned short)bf16rn(acc2[s][t][j]);
            }
        }
    }
}

// ---------------- launch ----------------

extern "C" void kernel_launch(void* const* d_in, const int* in_sizes, int n_in,
                              void* d_out, int out_size, void* d_ws, size_t ws_size,
                              hipStream_t stream) {
    const float* x   = (const float*)d_in[0];
    const int*   ei  = (const int*)d_in[1];
    const int*   src = ei;
    const int*   dst = ei + N_EDGES;
    const float* W1  = (const float*)d_in[3];
    const float* b1  = (const float*)d_in[4];
    const float* W2  = (const float*)d_in[5];
    const float* b2  = (const float*)d_in[6];
    float* out = (float*)d_out;

    char* ws = (char*)d_ws;
    size_t o = 0;
    auto carve = [&](size_t bytes) {
        void* p = ws + o;
        o += (bytes + 255) & ~(size_t)255;
        return p;
    };
    int*   cnt2D  = (int*)  carve((size_t)CNT2D * 4);
    int*   incl2D = (int*)  carve((size_t)(CNT2D + 1) * 4);  // becomes off2D
    int*   part   = (int*)  carve(SCAN_BLK * 4);
    int*   off    = (int*)  carve((size_t)(N_NODES + 1) * 4);
    float* dis    = (float*)carve(N_NODES * 4);
    int*   col    = (int*)  carve((size_t)TOTAL_E * 4);
    char*  buf1   = (char*) carve((size_t)N_NODES * 128 * 2);  // binned / agg1b
    unsigned short* bfbuf = (unsigned short*)carve((size_t)N_NODES * 128 * 2);
    u32x4* Wf1    = (u32x4*)carve((size_t)4 * 16 * 2 * 64 * 16);
    u32x4* Wf2    = (u32x4*)carve((size_t)8 * 8 * 2 * 64 * 16);
    int*   off2D  = incl2D;                // in-place exclusive scan
    // Aliases (lifetimes by launch order):
    //   binned aliases buf1 : written by k_bin (6.4 MB), read by k_csr, dead after
    //   agg1b  aliases buf1 : written by agg1 (12.8 MB, after binned dead)
    //   xb  = bfbuf         : written by k_tobf, read by agg1, dead after
    //   t2b = bfbuf         : written by fused gemm (xb dead), read by agg2
    int2*           binned = (int2*)buf1;
    unsigned short* agg1b  = (unsigned short*)buf1;
    unsigned short* xb     = bfbuf;
    unsigned short* t2b    = bfbuf;

    const int B = 256;
    k_tobf  <<<(N_NODES * 128 / 8 + B - 1) / B, B, 0, stream>>>(x, xb, N_NODES * 128 / 8);
    k_count <<<NBLK_BIN, 256, 0, stream>>>(dst, cnt2D);
    k_scan1 <<<NB_SC, SCAN_BLK, 0, stream>>>(cnt2D, incl2D, part, CNT2D);
    k_scan2 <<<1, SCAN_BLK, 0, stream>>>(part, NB_SC);
    k_off   <<<(CNT2D + 1 + B - 1) / B, B, 0, stream>>>(incl2D, cnt2D, part, CNT2D, N_EDGES);
    k_bin   <<<NBLK_BIN, 256, 0, stream>>>(src, dst, off2D, binned);
    k_csr   <<<NBKT, 256, 0, stream>>>(binned, off2D, col, off, dis);
    k_wsplit_both<<<32, 256, 0, stream>>>(W1, Wf1, W2, Wf2);

    // layer 1 aggregation: agg1b = bf16(A xb)   (overwrites binned, now dead)
    k_agg_bf<false, false, true><<<N_NODES / 4, 256, 0, stream>>>(
        xb, col, off, dis, nullptr, agg1b);
    // fused GEMMs: t2b = bf16( relu(agg1b@W1+b1) @ W2 )   (overwrites xb, now dead)
    k_gemm_fused<<<(N_NODES + 31) / 32, 256, 0, stream>>>(agg1b, Wf1, b1, Wf2, t2b, N_NODES);
    // layer 2 aggregation: out = relu(A t2b + b2)
    k_agg_bf<true, true, false><<<N_NODES / 4, 256, 0, stream>>>(
        t2b, col, off, dis, b2, out);
}